// Round 17
// baseline (277.126 us; speedup 1.0000x reference)
//
#include <hip/hip_runtime.h>
#include <hip/hip_bf16.h>
#include <math.h>

namespace {

constexpr int D  = 128;
constexpr int TN = 64;
constexpr int NB = 8;     // batches per fused block

__device__ __forceinline__ unsigned pack_bf2(float a, float b) {
    __hip_bfloat162 h = __float22bfloat162_rn(make_float2(a, b));
    return *reinterpret_cast<unsigned*>(&h);
}
__device__ __forceinline__ float lo_f(unsigned u) { return __uint_as_float(u << 16); }
__device__ __forceinline__ float hi_f(unsigned u) { return __uint_as_float(u & 0xffff0000u); }
__device__ __forceinline__ float bfs(unsigned short s) { return __uint_as_float((unsigned)s << 16); }
__device__ __forceinline__ float4 unp4(uint2 u) {
    return make_float4(lo_f(u.x), hi_f(u.x), lo_f(u.y), hi_f(u.y));
}
__device__ __forceinline__ int rot32(int fc) { return ((fc & 7) << 2) | (fc >> 3); }

// d_ws layout: N_bf16 [128][1024] (256 KB) + M_bf16 [1024][128] (256 KB)

// ---------------- K0: precompute N and M in BF16 (r16-proven) ----------------
__global__ __launch_bounds__(256)
void k0_nm(const float* __restrict__ WQ, const float* __restrict__ WK,
           const float* __restrict__ WV, const float* __restrict__ WO,
           unsigned short* __restrict__ Nb, unsigned short* __restrict__ Mb)
{
    const int t = blockIdx.x * 256 + threadIdx.x;   // 0..131071
    {
        const int k = t >> 10, col = t & 1023;
        const int h = col >> 7, d = col & 127;
        const float* wq = WQ + (size_t)k * D + h * 16;
        const float* wk = WK + (size_t)d * D + h * 16;
        float a = 0.f;
        #pragma unroll
        for (int j = 0; j < 16; ++j) a = fmaf(wq[j], wk[j], a);
        Nb[t] = (unsigned short)(pack_bf2(0.25f * a, 0.f) & 0xffffu);
    }
    {
        const int row = t >> 7, e = t & 127;
        const int h = row >> 7, d = row & 127;
        const float* wv = WV + (size_t)d * D + h * 16;
        const float* wo = WO + (size_t)(h * 16) * D + e;
        float a = 0.f;
        #pragma unroll
        for (int j = 0; j < 16; ++j) a = fmaf(wv[j], wo[(size_t)j * D], a);
        Mb[t] = (unsigned short)(pack_bf2(a, 0.f) & 0xffffu);
    }
}

// ---------------- fused: qk=c@N -> 8x attention (r11/r13 body) -> out=s@M ----------------
// LDS 39.3 KB -> 4 blocks/CU. bf16 qk/s/nb in LDS; simple unroll-4 GEMM loops (no hoist
// blowup, r16-proven); register-staged nb prefetch (r14 mechanism, free at this LDS cap).
__global__ __launch_bounds__(256, 4)
void k_fused(const float* __restrict__ center, const float* __restrict__ neighbors,
             const unsigned short* __restrict__ Nb, const unsigned short* __restrict__ Mb,
             float* __restrict__ out)
{
    __shared__ __align__(16) float nb_lds[TN * D / 2];  // 16 KB bf16 tokens; uint2 slot (t<<5)|(fc^(t&7))
    __shared__ __align__(16) float qs8f[NB * 512];      // 16 KB bf16: qk (rotated) -> s (linear), per batch
    __shared__ __align__(16) float c8[NB * D];          // 4 KB f32, rotated per row
    __shared__ float P_lds[TN * 12];                    // 3 KB
    __shared__ float red_pc[8];

    const int tid = threadIdx.x;           // 0..255
    const int w   = tid >> 6;              // wave 0..3 (attention: owns heads 2w,2w+1)
    const int l   = tid & 63;
    const size_t rb = (size_t)blockIdx.x * NB;

    uint2* nbu  = (uint2*)nb_lds;
    uint2* qs8u = (uint2*)qs8f;

    // ---- stage c8 (rotated) + issue batch-0 nb loads into staging regs ----
    {
        const int r = tid >> 5, f = tid & 31;
        ((float4*)c8)[r * 32 + rot32(f)] =
            ((const float4*)(center + (rb + r) * (size_t)D))[f];
    }
    float4 st[8];
    {
        const float4* g0 = (const float4*)(neighbors + rb * TN * D);
        #pragma unroll
        for (int i = 0; i < 8; ++i) st[i] = g0[i * 256 + tid];
    }
    __syncthreads();                       // c8 visible

    // ================= k1-part: qk8 = c8 @ N_bf16 (simple loop) =================
    {
        const uint2* Np = (const uint2*)Nb + tid;   // N row = 256 uint2
        float4 acc[NB];
        #pragma unroll
        for (int r = 0; r < NB; ++r) acc[r] = make_float4(0.f, 0.f, 0.f, 0.f);

        #pragma unroll 4
        for (int k = 0; k < 128; ++k) {
            const uint2 u = Np[(size_t)k * 256];
            const float4 nv = unp4(u);
            const int ca = rot32(k >> 2) * 4 + (k & 3);   // rotated c addr (uniform)
            #pragma unroll
            for (int r = 0; r < NB; ++r) {
                const float cc = c8[r * 128 + ca];        // broadcast
                acc[r].x = fmaf(cc, nv.x, acc[r].x);
                acc[r].y = fmaf(cc, nv.y, acc[r].y);
                acc[r].z = fmaf(cc, nv.z, acc[r].z);
                acc[r].w = fmaf(cc, nv.w, acc[r].w);
            }
        }
        const int qslot = (tid & ~31) | rot32(tid & 31);  // rotated qk layout
        #pragma unroll
        for (int r = 0; r < NB; ++r)
            qs8u[r * 256 + qslot] =
                make_uint2(pack_bf2(acc[r].x, acc[r].y), pack_bf2(acc[r].z, acc[r].w));
    }
    __syncthreads();                       // qk visible

    // ================= per-batch attention loop (r11/r13-proven body) =================
    #pragma unroll 1
    for (int bb = 0; bb < NB; ++bb) {
        // ---- commit staged nb registers -> bf16 swizzled LDS ----
        #pragma unroll
        for (int i = 0; i < 8; ++i) {
            const int fi = i * 256 + tid;
            const int t  = fi >> 5;
            const int fc = fi & 31;
            nbu[(t << 5) | (fc ^ (t & 7))] =
                make_uint2(pack_bf2(st[i].x, st[i].y), pack_bf2(st[i].z, st[i].w));
        }
        __syncthreads();                   // nb staged

        // ---- issue next batch's nb loads; they fly during phases A-E ----
        if (bb + 1 < NB) {
            const float4* gn = (const float4*)(neighbors + (rb + bb + 1) * TN * D);
            #pragma unroll
            for (int i = 0; i < 8; ++i) st[i] = gn[i * 256 + tid];
        }

        const uint2*  nb2 = (const uint2*)nb_lds;
        const uint2*  qku = qs8u + bb * 256;
        const float4* c4r = (const float4*)(c8 + bb * D);

        // ---- phase A: wave w scores all 64 tokens for heads 2w,2w+1; wave-local softmax ----
        const int tg = l & 15;
        const int q  = l >> 4;
        const int h0 = 2 * w;

        float sc0[4] = {0.f, 0.f, 0.f, 0.f};
        float sc1[4] = {0.f, 0.f, 0.f, 0.f};
        float s0a = 0.f, s0b = 0.f;
        #pragma unroll
        for (int jj = 0; jj < 8; ++jj) {
            const int rfc = (jj << 2) | q;     // rotated slot of fc=(q<<3)|jj
            const int fc  = (q << 3) | jj;
            const float4 kv0 = unp4(qku[h0 * 32 + rfc]);
            const float4 kv1 = unp4(qku[(h0 + 1) * 32 + rfc]);
            const float4 cc  = c4r[rfc];
            s0a = fmaf(cc.x, kv0.x, fmaf(cc.y, kv0.y, fmaf(cc.z, kv0.z, fmaf(cc.w, kv0.w, s0a))));
            s0b = fmaf(cc.x, kv1.x, fmaf(cc.y, kv1.y, fmaf(cc.z, kv1.z, fmaf(cc.w, kv1.w, s0b))));
            #pragma unroll
            for (int k = 0; k < 4; ++k) {
                const int t = tg + (k << 4);
                const uint2 u = nb2[(t << 5) | (fc ^ (t & 7))];
                const float t0 = lo_f(u.x), t1 = hi_f(u.x), t2 = lo_f(u.y), t3 = hi_f(u.y);
                sc0[k] = fmaf(t0, kv0.x, fmaf(t1, kv0.y, fmaf(t2, kv0.z, fmaf(t3, kv0.w, sc0[k]))));
                sc1[k] = fmaf(t0, kv1.x, fmaf(t1, kv1.y, fmaf(t2, kv1.z, fmaf(t3, kv1.w, sc1[k]))));
            }
        }
        #pragma unroll
        for (int k = 0; k < 4; ++k) {
            sc0[k] += __shfl_xor(sc0[k], 16);  sc0[k] += __shfl_xor(sc0[k], 32);
            sc1[k] += __shfl_xor(sc1[k], 16);  sc1[k] += __shfl_xor(sc1[k], 32);
        }
        s0a += __shfl_xor(s0a, 16);  s0a += __shfl_xor(s0a, 32);
        s0b += __shfl_xor(s0b, 16);  s0b += __shfl_xor(s0b, 32);

        float m0 = fmaxf(fmaxf(sc0[0], sc0[1]), fmaxf(sc0[2], sc0[3]));
        float m1 = fmaxf(fmaxf(sc1[0], sc1[1]), fmaxf(sc1[2], sc1[3]));
        #pragma unroll
        for (int off = 8; off >= 1; off >>= 1) {
            m0 = fmaxf(m0, __shfl_xor(m0, off));
            m1 = fmaxf(m1, __shfl_xor(m1, off));
        }
        m0 = fmaxf(m0, s0a);
        m1 = fmaxf(m1, s0b);
        float e0v[4], e1v[4];
        float sum0 = 0.f, sum1 = 0.f;
        #pragma unroll
        for (int k = 0; k < 4; ++k) {
            e0v[k] = __expf(sc0[k] - m0);  sum0 += e0v[k];
            e1v[k] = __expf(sc1[k] - m1);  sum1 += e1v[k];
        }
        #pragma unroll
        for (int off = 8; off >= 1; off >>= 1) {
            sum0 += __shfl_xor(sum0, off);
            sum1 += __shfl_xor(sum1, off);
        }
        const float ec0 = __expf(s0a - m0);
        const float ec1 = __expf(s0b - m1);
        const float inv0 = 1.0f / (sum0 + ec0);
        const float inv1 = 1.0f / (sum1 + ec1);
        if (q == 0) {
            #pragma unroll
            for (int k = 0; k < 4; ++k) {
                const int t = tg + (k << 4);
                *reinterpret_cast<float2*>(&P_lds[t * 12 + h0]) =
                    make_float2(e0v[k] * inv0, e1v[k] * inv1);
            }
            if (tg == 0) {
                red_pc[h0]     = ec0 * inv0;
                red_pc[h0 + 1] = ec1 * inv1;
            }
        }
        __syncthreads();   // bar: P complete

        // ---- phase D: wave w sums its 16 tokens; lane = (h-half, f4 col) ----
        const int hl  = l >> 5;
        const int fc2 = l & 31;
        float4 pacc[4];
        #pragma unroll
        for (int j = 0; j < 4; ++j) pacc[j] = make_float4(0.f, 0.f, 0.f, 0.f);
        #pragma unroll
        for (int tt = 0; tt < 16; ++tt) {
            const int t = w * 16 + tt;
            const uint2 u = nb2[(t << 5) | (fc2 ^ (t & 7))];
            const float t0 = lo_f(u.x), t1 = hi_f(u.x), t2 = lo_f(u.y), t3 = hi_f(u.y);
            const float4 pv = ((const float4*)P_lds)[t * 3 + hl];
            pacc[0].x = fmaf(pv.x, t0, pacc[0].x); pacc[0].y = fmaf(pv.x, t1, pacc[0].y);
            pacc[0].z = fmaf(pv.x, t2, pacc[0].z); pacc[0].w = fmaf(pv.x, t3, pacc[0].w);
            pacc[1].x = fmaf(pv.y, t0, pacc[1].x); pacc[1].y = fmaf(pv.y, t1, pacc[1].y);
            pacc[1].z = fmaf(pv.y, t2, pacc[1].z); pacc[1].w = fmaf(pv.y, t3, pacc[1].w);
            pacc[2].x = fmaf(pv.z, t0, pacc[2].x); pacc[2].y = fmaf(pv.z, t1, pacc[2].y);
            pacc[2].z = fmaf(pv.z, t2, pacc[2].z); pacc[2].w = fmaf(pv.z, t3, pacc[2].w);
            pacc[3].x = fmaf(pv.w, t0, pacc[3].x); pacc[3].y = fmaf(pv.w, t1, pacc[3].y);
            pacc[3].z = fmaf(pv.w, t2, pacc[3].z); pacc[3].w = fmaf(pv.w, t3, pacc[3].w);
        }
        // partials (f32) overlay the wave's OWN dead bf16 token rows (4 KB each)
        #pragma unroll
        for (int j = 0; j < 4; ++j)
            ((float4*)nb_lds)[w * 256 + (hl * 4 + j) * 32 + fc2] = pacc[j];
        __syncthreads();   // bar: partials ready

        // ---- phase E: combine partials + center seed; write s (bf16, linear) ----
        {
            const int hE = tid >> 5;
            const int fE = tid & 31;
            float4 sum = make_float4(0.f, 0.f, 0.f, 0.f);
            #pragma unroll
            for (int ww = 0; ww < 4; ++ww) {
                const float4 p = ((const float4*)nb_lds)[ww * 256 + hE * 32 + fE];
                sum.x += p.x; sum.y += p.y; sum.z += p.z; sum.w += p.w;
            }
            const float pc = red_pc[hE];
            const float4 cc = c4r[rot32(fE)];
            sum.x = fmaf(pc, cc.x, sum.x);
            sum.y = fmaf(pc, cc.y, sum.y);
            sum.z = fmaf(pc, cc.z, sum.z);
            sum.w = fmaf(pc, cc.w, sum.w);
            qs8u[bb * 256 + tid] =
                make_uint2(pack_bf2(sum.x, sum.y), pack_bf2(sum.z, sum.w));
        }
        __syncthreads();   // bar: partials consumed; next commit may overwrite nb
    }

    // ================= k3-part: out = s8 @ M_bf16 (simple loop) =================
    {
        const int cg = tid & 31;
        const int kg = tid >> 5;
        const int c4i = cg << 2;
        const int kbase = kg << 7;

        float4 acc[NB];
        #pragma unroll
        for (int r = 0; r < NB; ++r) acc[r] = make_float4(0.f, 0.f, 0.f, 0.f);

        const uint2* Mp2 = (const uint2*)Mb;
        const unsigned short* sp = (const unsigned short*)qs8f;

        #pragma unroll 4
        for (int ki = 0; ki < 128; ++ki) {
            const int k = kbase + ki;
            const uint2 u = Mp2[(size_t)k * 32 + cg];
            const float4 mv = unp4(u);
            #pragma unroll
            for (int r = 0; r < NB; ++r) {
                const float sv = bfs(sp[r * 1024 + k]);   // broadcast within group
                acc[r].x = fmaf(sv, mv.x, acc[r].x);
                acc[r].y = fmaf(sv, mv.y, acc[r].y);
                acc[r].z = fmaf(sv, mv.z, acc[r].z);
                acc[r].w = fmaf(sv, mv.w, acc[r].w);
            }
        }
        __syncthreads();                   // all s reads done; nb+qs8 regions free
        // partials: 32 KB split across nb_lds (kg 0-3) and qs8f (kg 4-7)
        float* baseW = (kg < 4) ? nb_lds : qs8f;
        const int kgm = kg & 3;
        #pragma unroll
        for (int r = 0; r < NB; ++r)
            *reinterpret_cast<float4*>(&baseW[(kgm * 8 + r) * 128 + c4i]) = acc[r];
        __syncthreads();

        {
            const int r = tid >> 5;
            float4 sum = make_float4(0.f, 0.f, 0.f, 0.f);
            #pragma unroll
            for (int g = 0; g < 8; ++g) {
                const float* bg = (g < 4) ? nb_lds : qs8f;
                const float4 p = *reinterpret_cast<const float4*>(
                    &bg[((g & 3) * 8 + r) * 128 + c4i]);
                sum.x += p.x; sum.y += p.y; sum.z += p.z; sum.w += p.w;
            }
            *reinterpret_cast<float4*>(out + (rb + r) * D + c4i) = sum;
        }
    }
}

} // namespace

extern "C" void kernel_launch(void* const* d_in, const int* in_sizes, int n_in,
                              void* d_out, int out_size, void* d_ws, size_t ws_size,
                              hipStream_t stream) {
    const float* center    = (const float*)d_in[0];
    const float* neighbors = (const float*)d_in[1];
    const float* WQ        = (const float*)d_in[2];
    const float* WK        = (const float*)d_in[3];
    const float* WV        = (const float*)d_in[4];
    const float* WO        = (const float*)d_in[5];
    float* outp            = (float*)d_out;

    const int B = in_sizes[0] / D;   // 8192

    unsigned short* Nb = (unsigned short*)d_ws;          // 128*1024 bf16 (256 KB)
    unsigned short* Mb = Nb + 128 * 1024;                // 1024*128 bf16 (256 KB)

    hipLaunchKernelGGL(k0_nm,   dim3(512),    dim3(256), 0, stream, WQ, WK, WV, WO, Nb, Mb);
    hipLaunchKernelGGL(k_fused, dim3(B / NB), dim3(256), 0, stream, center, neighbors, Nb, Mb, outp);
}

// Round 18
// 141.827 us; speedup vs baseline: 1.9540x; 1.9540x over previous
//
#include <hip/hip_runtime.h>
#include <hip/hip_bf16.h>
#include <math.h>

namespace {

constexpr int D  = 128;
constexpr int TN = 64;
constexpr int NB = 8;     // batches per fused block

__device__ __forceinline__ unsigned pack_bf2(float a, float b) {
    __hip_bfloat162 h = __float22bfloat162_rn(make_float2(a, b));
    return *reinterpret_cast<unsigned*>(&h);
}
__device__ __forceinline__ float lo_f(unsigned u) { return __uint_as_float(u << 16); }
__device__ __forceinline__ float hi_f(unsigned u) { return __uint_as_float(u & 0xffff0000u); }
__device__ __forceinline__ float bfs(unsigned short s) { return __uint_as_float((unsigned)s << 16); }
__device__ __forceinline__ float4 unp4(uint2 u) {
    return make_float4(lo_f(u.x), hi_f(u.x), lo_f(u.y), hi_f(u.y));
}
__device__ __forceinline__ int rot32(int fc) { return ((fc & 7) << 2) | (fc >> 3); }

// d_ws layout: N_bf16 [128][1024] (256 KB) + M_bf16 [1024][128] (256 KB)

// ---------------- K0: precompute N and M in BF16 (r16-proven) ----------------
__global__ __launch_bounds__(256)
void k0_nm(const float* __restrict__ WQ, const float* __restrict__ WK,
           const float* __restrict__ WV, const float* __restrict__ WO,
           unsigned short* __restrict__ Nb, unsigned short* __restrict__ Mb)
{
    const int t = blockIdx.x * 256 + threadIdx.x;   // 0..131071
    {
        const int k = t >> 10, col = t & 1023;
        const int h = col >> 7, d = col & 127;
        const float* wq = WQ + (size_t)k * D + h * 16;
        const float* wk = WK + (size_t)d * D + h * 16;
        float a = 0.f;
        #pragma unroll
        for (int j = 0; j < 16; ++j) a = fmaf(wq[j], wk[j], a);
        Nb[t] = (unsigned short)(pack_bf2(0.25f * a, 0.f) & 0xffffu);
    }
    {
        const int row = t >> 7, e = t & 127;
        const int h = row >> 7, d = row & 127;
        const float* wv = WV + (size_t)d * D + h * 16;
        const float* wo = WO + (size_t)(h * 16) * D + e;
        float a = 0.f;
        #pragma unroll
        for (int j = 0; j < 16; ++j) a = fmaf(wv[j], wo[(size_t)j * D], a);
        Mb[t] = (unsigned short)(pack_bf2(a, 0.f) & 0xffffu);
    }
}

// ---------------- fused: qk=c@N -> 8x attention -> out=s@M (r17 logic, spill-fixed) -------
// Fix 1: batch-0 staging regs loaded AFTER the k1 GEMM (not live across it).
// Fix 2: __launch_bounds__(256,2) -> VGPR budget 256; stops the 64-VGPR self-spill.
// LDS 39.3 KB -> 4 blocks/CU while VGPR <= 128.
__global__ __launch_bounds__(256, 2)
void k_fused(const float* __restrict__ center, const float* __restrict__ neighbors,
             const unsigned short* __restrict__ Nb, const unsigned short* __restrict__ Mb,
             float* __restrict__ out)
{
    __shared__ __align__(16) float nb_lds[TN * D / 2];  // 16 KB bf16 tokens; uint2 slot (t<<5)|(fc^(t&7))
    __shared__ __align__(16) float qs8f[NB * 512];      // 16 KB bf16: qk (rotated) -> s (linear), per batch
    __shared__ __align__(16) float c8[NB * D];          // 4 KB f32, rotated per row
    __shared__ float P_lds[TN * 12];                    // 3 KB
    __shared__ float red_pc[8];

    const int tid = threadIdx.x;           // 0..255
    const int w   = tid >> 6;              // wave 0..3 (attention: owns heads 2w,2w+1)
    const int l   = tid & 63;
    const size_t rb = (size_t)blockIdx.x * NB;

    uint2* nbu  = (uint2*)nb_lds;
    uint2* qs8u = (uint2*)qs8f;

    // ---- stage c8 (rotated) ----
    {
        const int r = tid >> 5, f = tid & 31;
        ((float4*)c8)[r * 32 + rot32(f)] =
            ((const float4*)(center + (rb + r) * (size_t)D))[f];
    }
    __syncthreads();                       // c8 visible

    // ================= k1-part: qk8 = c8 @ N_bf16 (simple loop, r16-proven) =================
    {
        const uint2* Np = (const uint2*)Nb + tid;   // N row = 256 uint2
        float4 acc[NB];
        #pragma unroll
        for (int r = 0; r < NB; ++r) acc[r] = make_float4(0.f, 0.f, 0.f, 0.f);

        #pragma unroll 4
        for (int k = 0; k < 128; ++k) {
            const uint2 u = Np[(size_t)k * 256];
            const float4 nv = unp4(u);
            const int ca = rot32(k >> 2) * 4 + (k & 3);   // rotated c addr (uniform)
            #pragma unroll
            for (int r = 0; r < NB; ++r) {
                const float cc = c8[r * 128 + ca];        // broadcast
                acc[r].x = fmaf(cc, nv.x, acc[r].x);
                acc[r].y = fmaf(cc, nv.y, acc[r].y);
                acc[r].z = fmaf(cc, nv.z, acc[r].z);
                acc[r].w = fmaf(cc, nv.w, acc[r].w);
            }
        }
        const int qslot = (tid & ~31) | rot32(tid & 31);  // rotated qk layout
        #pragma unroll
        for (int r = 0; r < NB; ++r)
            qs8u[r * 256 + qslot] =
                make_uint2(pack_bf2(acc[r].x, acc[r].y), pack_bf2(acc[r].z, acc[r].w));
    }

    // ---- NOW load batch-0 nb into staging regs (not live across the GEMM above) ----
    float4 st[8];
    {
        const float4* g0 = (const float4*)(neighbors + rb * TN * D);
        #pragma unroll
        for (int i = 0; i < 8; ++i) st[i] = g0[i * 256 + tid];
    }
    __syncthreads();                       // qk visible

    // ================= per-batch attention loop (r17-proven logic) =================
    #pragma unroll 1
    for (int bb = 0; bb < NB; ++bb) {
        // ---- commit staged nb registers -> bf16 swizzled LDS ----
        #pragma unroll
        for (int i = 0; i < 8; ++i) {
            const int fi = i * 256 + tid;
            const int t  = fi >> 5;
            const int fc = fi & 31;
            nbu[(t << 5) | (fc ^ (t & 7))] =
                make_uint2(pack_bf2(st[i].x, st[i].y), pack_bf2(st[i].z, st[i].w));
        }
        __syncthreads();                   // nb staged

        // ---- issue next batch's nb loads; they fly during phases A-E ----
        if (bb + 1 < NB) {
            const float4* gn = (const float4*)(neighbors + (rb + bb + 1) * TN * D);
            #pragma unroll
            for (int i = 0; i < 8; ++i) st[i] = gn[i * 256 + tid];
        }

        const uint2*  nb2 = (const uint2*)nb_lds;
        const uint2*  qku = qs8u + bb * 256;
        const float4* c4r = (const float4*)(c8 + bb * D);

        // ---- phase A: wave w scores all 64 tokens for heads 2w,2w+1; wave-local softmax ----
        const int tg = l & 15;
        const int q  = l >> 4;
        const int h0 = 2 * w;

        float sc0[4] = {0.f, 0.f, 0.f, 0.f};
        float sc1[4] = {0.f, 0.f, 0.f, 0.f};
        float s0a = 0.f, s0b = 0.f;
        #pragma unroll
        for (int jj = 0; jj < 8; ++jj) {
            const int rfc = (jj << 2) | q;     // rotated slot of fc=(q<<3)|jj
            const int fc  = (q << 3) | jj;
            const float4 kv0 = unp4(qku[h0 * 32 + rfc]);
            const float4 kv1 = unp4(qku[(h0 + 1) * 32 + rfc]);
            const float4 cc  = c4r[rfc];
            s0a = fmaf(cc.x, kv0.x, fmaf(cc.y, kv0.y, fmaf(cc.z, kv0.z, fmaf(cc.w, kv0.w, s0a))));
            s0b = fmaf(cc.x, kv1.x, fmaf(cc.y, kv1.y, fmaf(cc.z, kv1.z, fmaf(cc.w, kv1.w, s0b))));
            #pragma unroll
            for (int k = 0; k < 4; ++k) {
                const int t = tg + (k << 4);
                const uint2 u = nb2[(t << 5) | (fc ^ (t & 7))];
                const float t0 = lo_f(u.x), t1 = hi_f(u.x), t2 = lo_f(u.y), t3 = hi_f(u.y);
                sc0[k] = fmaf(t0, kv0.x, fmaf(t1, kv0.y, fmaf(t2, kv0.z, fmaf(t3, kv0.w, sc0[k]))));
                sc1[k] = fmaf(t0, kv1.x, fmaf(t1, kv1.y, fmaf(t2, kv1.z, fmaf(t3, kv1.w, sc1[k]))));
            }
        }
        #pragma unroll
        for (int k = 0; k < 4; ++k) {
            sc0[k] += __shfl_xor(sc0[k], 16);  sc0[k] += __shfl_xor(sc0[k], 32);
            sc1[k] += __shfl_xor(sc1[k], 16);  sc1[k] += __shfl_xor(sc1[k], 32);
        }
        s0a += __shfl_xor(s0a, 16);  s0a += __shfl_xor(s0a, 32);
        s0b += __shfl_xor(s0b, 16);  s0b += __shfl_xor(s0b, 32);

        float m0 = fmaxf(fmaxf(sc0[0], sc0[1]), fmaxf(sc0[2], sc0[3]));
        float m1 = fmaxf(fmaxf(sc1[0], sc1[1]), fmaxf(sc1[2], sc1[3]));
        #pragma unroll
        for (int off = 8; off >= 1; off >>= 1) {
            m0 = fmaxf(m0, __shfl_xor(m0, off));
            m1 = fmaxf(m1, __shfl_xor(m1, off));
        }
        m0 = fmaxf(m0, s0a);
        m1 = fmaxf(m1, s0b);
        float e0v[4], e1v[4];
        float sum0 = 0.f, sum1 = 0.f;
        #pragma unroll
        for (int k = 0; k < 4; ++k) {
            e0v[k] = __expf(sc0[k] - m0);  sum0 += e0v[k];
            e1v[k] = __expf(sc1[k] - m1);  sum1 += e1v[k];
        }
        #pragma unroll
        for (int off = 8; off >= 1; off >>= 1) {
            sum0 += __shfl_xor(sum0, off);
            sum1 += __shfl_xor(sum1, off);
        }
        const float ec0 = __expf(s0a - m0);
        const float ec1 = __expf(s0b - m1);
        const float inv0 = 1.0f / (sum0 + ec0);
        const float inv1 = 1.0f / (sum1 + ec1);
        if (q == 0) {
            #pragma unroll
            for (int k = 0; k < 4; ++k) {
                const int t = tg + (k << 4);
                *reinterpret_cast<float2*>(&P_lds[t * 12 + h0]) =
                    make_float2(e0v[k] * inv0, e1v[k] * inv1);
            }
            if (tg == 0) {
                red_pc[h0]     = ec0 * inv0;
                red_pc[h0 + 1] = ec1 * inv1;
            }
        }
        __syncthreads();   // bar: P complete

        // ---- phase D: wave w sums its 16 tokens; lane = (h-half, f4 col) ----
        const int hl  = l >> 5;
        const int fc2 = l & 31;
        float4 pacc[4];
        #pragma unroll
        for (int j = 0; j < 4; ++j) pacc[j] = make_float4(0.f, 0.f, 0.f, 0.f);
        #pragma unroll
        for (int tt = 0; tt < 16; ++tt) {
            const int t = w * 16 + tt;
            const uint2 u = nb2[(t << 5) | (fc2 ^ (t & 7))];
            const float t0 = lo_f(u.x), t1 = hi_f(u.x), t2 = lo_f(u.y), t3 = hi_f(u.y);
            const float4 pv = ((const float4*)P_lds)[t * 3 + hl];
            pacc[0].x = fmaf(pv.x, t0, pacc[0].x); pacc[0].y = fmaf(pv.x, t1, pacc[0].y);
            pacc[0].z = fmaf(pv.x, t2, pacc[0].z); pacc[0].w = fmaf(pv.x, t3, pacc[0].w);
            pacc[1].x = fmaf(pv.y, t0, pacc[1].x); pacc[1].y = fmaf(pv.y, t1, pacc[1].y);
            pacc[1].z = fmaf(pv.y, t2, pacc[1].z); pacc[1].w = fmaf(pv.y, t3, pacc[1].w);
            pacc[2].x = fmaf(pv.z, t0, pacc[2].x); pacc[2].y = fmaf(pv.z, t1, pacc[2].y);
            pacc[2].z = fmaf(pv.z, t2, pacc[2].z); pacc[2].w = fmaf(pv.z, t3, pacc[2].w);
            pacc[3].x = fmaf(pv.w, t0, pacc[3].x); pacc[3].y = fmaf(pv.w, t1, pacc[3].y);
            pacc[3].z = fmaf(pv.w, t2, pacc[3].z); pacc[3].w = fmaf(pv.w, t3, pacc[3].w);
        }
        // partials (f32) overlay the wave's OWN dead bf16 token rows (4 KB each)
        #pragma unroll
        for (int j = 0; j < 4; ++j)
            ((float4*)nb_lds)[w * 256 + (hl * 4 + j) * 32 + fc2] = pacc[j];
        __syncthreads();   // bar: partials ready

        // ---- phase E: combine partials + center seed; write s (bf16, linear) ----
        {
            const int hE = tid >> 5;
            const int fE = tid & 31;
            float4 sum = make_float4(0.f, 0.f, 0.f, 0.f);
            #pragma unroll
            for (int ww = 0; ww < 4; ++ww) {
                const float4 p = ((const float4*)nb_lds)[ww * 256 + hE * 32 + fE];
                sum.x += p.x; sum.y += p.y; sum.z += p.z; sum.w += p.w;
            }
            const float pc = red_pc[hE];
            const float4 cc = c4r[rot32(fE)];
            sum.x = fmaf(pc, cc.x, sum.x);
            sum.y = fmaf(pc, cc.y, sum.y);
            sum.z = fmaf(pc, cc.z, sum.z);
            sum.w = fmaf(pc, cc.w, sum.w);
            qs8u[bb * 256 + tid] =
                make_uint2(pack_bf2(sum.x, sum.y), pack_bf2(sum.z, sum.w));
        }
        __syncthreads();   // bar: partials consumed; next commit may overwrite nb
    }

    // ================= k3-part: out = s8 @ M_bf16 (simple loop, r16-proven) =================
    {
        const int cg = tid & 31;
        const int kg = tid >> 5;
        const int c4i = cg << 2;
        const int kbase = kg << 7;

        float4 acc[NB];
        #pragma unroll
        for (int r = 0; r < NB; ++r) acc[r] = make_float4(0.f, 0.f, 0.f, 0.f);

        const uint2* Mp2 = (const uint2*)Mb;
        const unsigned short* sp = (const unsigned short*)qs8f;

        #pragma unroll 4
        for (int ki = 0; ki < 128; ++ki) {
            const int k = kbase + ki;
            const uint2 u = Mp2[(size_t)k * 32 + cg];
            const float4 mv = unp4(u);
            #pragma unroll
            for (int r = 0; r < NB; ++r) {
                const float sv = bfs(sp[r * 1024 + k]);   // broadcast within group
                acc[r].x = fmaf(sv, mv.x, acc[r].x);
                acc[r].y = fmaf(sv, mv.y, acc[r].y);
                acc[r].z = fmaf(sv, mv.z, acc[r].z);
                acc[r].w = fmaf(sv, mv.w, acc[r].w);
            }
        }
        __syncthreads();                   // all s reads done; nb+qs8 regions free
        // partials: 32 KB split across nb_lds (kg 0-3) and qs8f (kg 4-7)
        float* baseW = (kg < 4) ? nb_lds : qs8f;
        const int kgm = kg & 3;
        #pragma unroll
        for (int r = 0; r < NB; ++r)
            *reinterpret_cast<float4*>(&baseW[(kgm * 8 + r) * 128 + c4i]) = acc[r];
        __syncthreads();

        {
            const int r = tid >> 5;
            float4 sum = make_float4(0.f, 0.f, 0.f, 0.f);
            #pragma unroll
            for (int g = 0; g < 8; ++g) {
                const float* bg = (g < 4) ? nb_lds : qs8f;
                const float4 p = *reinterpret_cast<const float4*>(
                    &bg[((g & 3) * 8 + r) * 128 + c4i]);
                sum.x += p.x; sum.y += p.y; sum.z += p.z; sum.w += p.w;
            }
            *reinterpret_cast<float4*>(out + (rb + r) * D + c4i) = sum;
        }
    }
}

} // namespace

extern "C" void kernel_launch(void* const* d_in, const int* in_sizes, int n_in,
                              void* d_out, int out_size, void* d_ws, size_t ws_size,
                              hipStream_t stream) {
    const float* center    = (const float*)d_in[0];
    const float* neighbors = (const float*)d_in[1];
    const float* WQ        = (const float*)d_in[2];
    const float* WK        = (const float*)d_in[3];
    const float* WV        = (const float*)d_in[4];
    const float* WO        = (const float*)d_in[5];
    float* outp            = (float*)d_out;

    const int B = in_sizes[0] / D;   // 8192

    unsigned short* Nb = (unsigned short*)d_ws;          // 128*1024 bf16 (256 KB)
    unsigned short* Mb = Nb + 128 * 1024;                // 1024*128 bf16 (256 KB)

    hipLaunchKernelGGL(k0_nm,   dim3(512),    dim3(256), 0, stream, WQ, WK, WV, WO, Nb, Mb);
    hipLaunchKernelGGL(k_fused, dim3(B / NB), dim3(256), 0, stream, center, neighbors, Nb, Mb, outp);
}

// Round 19
// 131.758 us; speedup vs baseline: 2.1033x; 1.0764x over previous
//
#include <hip/hip_runtime.h>
#include <hip/hip_bf16.h>
#include <math.h>

namespace {

constexpr int D  = 128;
constexpr int TN = 64;
constexpr int NB = 8;     // batches per fused block

typedef _Float16 h2 __attribute__((ext_vector_type(2)));

__device__ __forceinline__ unsigned pack_bf2(float a, float b) {
    __hip_bfloat162 h = __float22bfloat162_rn(make_float2(a, b));
    return *reinterpret_cast<unsigned*>(&h);
}
__device__ __forceinline__ float bfs(unsigned short s) { return __uint_as_float((unsigned)s << 16); }
__device__ __forceinline__ float lo_f(unsigned u) { return __uint_as_float(u << 16); }
__device__ __forceinline__ float hi_f(unsigned u) { return __uint_as_float(u & 0xffff0000u); }
__device__ __forceinline__ float4 unp4(uint2 u) {
    return make_float4(lo_f(u.x), hi_f(u.x), lo_f(u.y), hi_f(u.y));
}
__device__ __forceinline__ int rot32(int fc) { return ((fc & 7) << 2) | (fc >> 3); }

// f16 pack/unpack + 2-way dot (v_dot2_f32_f16)
__device__ __forceinline__ unsigned pack_h2(float a, float b) {
    h2 v; v.x = (_Float16)a; v.y = (_Float16)b;
    return __builtin_bit_cast(unsigned, v);
}
__device__ __forceinline__ float2 unp_h2(unsigned u) {
    h2 v = __builtin_bit_cast(h2, u);
    return make_float2((float)v.x, (float)v.y);
}
__device__ __forceinline__ float fdot2f(unsigned a, unsigned b, float c) {
#if __has_builtin(__builtin_amdgcn_fdot2)
    return __builtin_amdgcn_fdot2(__builtin_bit_cast(h2, a),
                                  __builtin_bit_cast(h2, b), c, false);
#else
    const float2 fa = unp_h2(a), fb = unp_h2(b);
    return fmaf(fa.x, fb.x, fmaf(fa.y, fb.y, c));
#endif
}

// d_ws layout: N_bf16 [128][1024] (256 KB) + M_bf16 [1024][128] (256 KB)

// ---------------- K0: precompute N and M in BF16 (r16-proven) ----------------
__global__ __launch_bounds__(256)
void k0_nm(const float* __restrict__ WQ, const float* __restrict__ WK,
           const float* __restrict__ WV, const float* __restrict__ WO,
           unsigned short* __restrict__ Nb, unsigned short* __restrict__ Mb)
{
    const int t = blockIdx.x * 256 + threadIdx.x;   // 0..131071
    {
        const int k = t >> 10, col = t & 1023;
        const int h = col >> 7, d = col & 127;
        const float* wq = WQ + (size_t)k * D + h * 16;
        const float* wk = WK + (size_t)d * D + h * 16;
        float a = 0.f;
        #pragma unroll
        for (int j = 0; j < 16; ++j) a = fmaf(wq[j], wk[j], a);
        Nb[t] = (unsigned short)(pack_bf2(0.25f * a, 0.f) & 0xffffu);
    }
    {
        const int row = t >> 7, e = t & 127;
        const int h = row >> 7, d = row & 127;
        const float* wv = WV + (size_t)d * D + h * 16;
        const float* wo = WO + (size_t)(h * 16) * D + e;
        float a = 0.f;
        #pragma unroll
        for (int j = 0; j < 16; ++j) a = fmaf(wv[j], wo[(size_t)j * D], a);
        Mb[t] = (unsigned short)(pack_bf2(a, 0.f) & 0xffffu);
    }
}

// ---------------- fused: qk=c@N -> 8x attention -> out=s@M (r18 + f16/fdot2) -------------
// r18's spill-free config preserved: batch-0 staging after k1 GEMM; launch_bounds(256,2).
// NEW: tokens + qk stored packed f16 in LDS; phase A uses v_dot2_f32_f16 (2 MAC/instr).
__global__ __launch_bounds__(256, 2)
void k_fused(const float* __restrict__ center, const float* __restrict__ neighbors,
             const unsigned short* __restrict__ Nb, const unsigned short* __restrict__ Mb,
             float* __restrict__ out)
{
    __shared__ __align__(16) float nb_lds[TN * D / 2];  // 16 KB f16 tokens; uint2 slot (t<<5)|(fc^(t&7))
    __shared__ __align__(16) float qs8f[NB * 512];      // 16 KB: qk f16 (rotated) -> s bf16 (linear)
    __shared__ __align__(16) float c8[NB * D];          // 4 KB f32, rotated per row
    __shared__ float P_lds[TN * 12];                    // 3 KB
    __shared__ float red_pc[8];

    const int tid = threadIdx.x;           // 0..255
    const int w   = tid >> 6;              // wave 0..3 (attention: owns heads 2w,2w+1)
    const int l   = tid & 63;
    const size_t rb = (size_t)blockIdx.x * NB;

    uint2* nbu  = (uint2*)nb_lds;
    uint2* qs8u = (uint2*)qs8f;

    // ---- stage c8 (rotated) ----
    {
        const int r = tid >> 5, f = tid & 31;
        ((float4*)c8)[r * 32 + rot32(f)] =
            ((const float4*)(center + (rb + r) * (size_t)D))[f];
    }
    __syncthreads();                       // c8 visible

    // ================= k1-part: qk8 = c8 @ N_bf16 (simple loop, r16-proven) =================
    {
        const uint2* Np = (const uint2*)Nb + tid;   // N row = 256 uint2
        float4 acc[NB];
        #pragma unroll
        for (int r = 0; r < NB; ++r) acc[r] = make_float4(0.f, 0.f, 0.f, 0.f);

        #pragma unroll 4
        for (int k = 0; k < 128; ++k) {
            const uint2 u = Np[(size_t)k * 256];
            const float4 nv = unp4(u);
            const int ca = rot32(k >> 2) * 4 + (k & 3);   // rotated c addr (uniform)
            #pragma unroll
            for (int r = 0; r < NB; ++r) {
                const float cc = c8[r * 128 + ca];        // broadcast
                acc[r].x = fmaf(cc, nv.x, acc[r].x);
                acc[r].y = fmaf(cc, nv.y, acc[r].y);
                acc[r].z = fmaf(cc, nv.z, acc[r].z);
                acc[r].w = fmaf(cc, nv.w, acc[r].w);
            }
        }
        const int qslot = (tid & ~31) | rot32(tid & 31);  // rotated qk layout, packed f16
        #pragma unroll
        for (int r = 0; r < NB; ++r)
            qs8u[r * 256 + qslot] =
                make_uint2(pack_h2(acc[r].x, acc[r].y), pack_h2(acc[r].z, acc[r].w));
    }

    // ---- NOW load batch-0 nb into staging regs (not live across the GEMM above) ----
    float4 st[8];
    {
        const float4* g0 = (const float4*)(neighbors + rb * TN * D);
        #pragma unroll
        for (int i = 0; i < 8; ++i) st[i] = g0[i * 256 + tid];
    }
    __syncthreads();                       // qk visible

    // ================= per-batch attention loop =================
    #pragma unroll 1
    for (int bb = 0; bb < NB; ++bb) {
        // ---- commit staged nb registers -> f16 swizzled LDS ----
        #pragma unroll
        for (int i = 0; i < 8; ++i) {
            const int fi = i * 256 + tid;
            const int t  = fi >> 5;
            const int fc = fi & 31;
            nbu[(t << 5) | (fc ^ (t & 7))] =
                make_uint2(pack_h2(st[i].x, st[i].y), pack_h2(st[i].z, st[i].w));
        }
        __syncthreads();                   // nb staged

        // ---- issue next batch's nb loads; they fly during phases A-E ----
        if (bb + 1 < NB) {
            const float4* gn = (const float4*)(neighbors + (rb + bb + 1) * TN * D);
            #pragma unroll
            for (int i = 0; i < 8; ++i) st[i] = gn[i * 256 + tid];
        }

        const uint2*  nb2 = (const uint2*)nb_lds;
        const uint2*  qku = qs8u + bb * 256;
        const float4* c4r = (const float4*)(c8 + bb * D);

        // ---- phase A: wave w scores all 64 tokens for heads 2w,2w+1; wave-local softmax ----
        const int tg = l & 15;
        const int q  = l >> 4;
        const int h0 = 2 * w;

        float sc0[4] = {0.f, 0.f, 0.f, 0.f};
        float sc1[4] = {0.f, 0.f, 0.f, 0.f};
        float s0a = 0.f, s0b = 0.f;
        #pragma unroll
        for (int jj = 0; jj < 8; ++jj) {
            const int rfc = (jj << 2) | q;     // rotated slot of fc=(q<<3)|jj
            const int fc  = (q << 3) | jj;
            const uint2 kv0p = qku[h0 * 32 + rfc];
            const uint2 kv1p = qku[(h0 + 1) * 32 + rfc];
            // s0: center (f32) . qk — unpack qk once per jj
            const float2 k0lo = unp_h2(kv0p.x), k0hi = unp_h2(kv0p.y);
            const float2 k1lo = unp_h2(kv1p.x), k1hi = unp_h2(kv1p.y);
            const float4 cc = c4r[rfc];
            s0a = fmaf(cc.x, k0lo.x, fmaf(cc.y, k0lo.y, fmaf(cc.z, k0hi.x, fmaf(cc.w, k0hi.y, s0a))));
            s0b = fmaf(cc.x, k1lo.x, fmaf(cc.y, k1lo.y, fmaf(cc.z, k1hi.x, fmaf(cc.w, k1hi.y, s0b))));
            // token scores: packed f16 dot2 (2 MAC/instr, zero unpack)
            #pragma unroll
            for (int k = 0; k < 4; ++k) {
                const int t = tg + (k << 4);
                const uint2 u = nb2[(t << 5) | (fc ^ (t & 7))];
                sc0[k] = fdot2f(u.x, kv0p.x, fdot2f(u.y, kv0p.y, sc0[k]));
                sc1[k] = fdot2f(u.x, kv1p.x, fdot2f(u.y, kv1p.y, sc1[k]));
            }
        }
        #pragma unroll
        for (int k = 0; k < 4; ++k) {
            sc0[k] += __shfl_xor(sc0[k], 16);  sc0[k] += __shfl_xor(sc0[k], 32);
            sc1[k] += __shfl_xor(sc1[k], 16);  sc1[k] += __shfl_xor(sc1[k], 32);
        }
        s0a += __shfl_xor(s0a, 16);  s0a += __shfl_xor(s0a, 32);
        s0b += __shfl_xor(s0b, 16);  s0b += __shfl_xor(s0b, 32);

        float m0 = fmaxf(fmaxf(sc0[0], sc0[1]), fmaxf(sc0[2], sc0[3]));
        float m1 = fmaxf(fmaxf(sc1[0], sc1[1]), fmaxf(sc1[2], sc1[3]));
        #pragma unroll
        for (int off = 8; off >= 1; off >>= 1) {
            m0 = fmaxf(m0, __shfl_xor(m0, off));
            m1 = fmaxf(m1, __shfl_xor(m1, off));
        }
        m0 = fmaxf(m0, s0a);
        m1 = fmaxf(m1, s0b);
        float e0v[4], e1v[4];
        float sum0 = 0.f, sum1 = 0.f;
        #pragma unroll
        for (int k = 0; k < 4; ++k) {
            e0v[k] = __expf(sc0[k] - m0);  sum0 += e0v[k];
            e1v[k] = __expf(sc1[k] - m1);  sum1 += e1v[k];
        }
        #pragma unroll
        for (int off = 8; off >= 1; off >>= 1) {
            sum0 += __shfl_xor(sum0, off);
            sum1 += __shfl_xor(sum1, off);
        }
        const float ec0 = __expf(s0a - m0);
        const float ec1 = __expf(s0b - m1);
        const float inv0 = 1.0f / (sum0 + ec0);
        const float inv1 = 1.0f / (sum1 + ec1);
        if (q == 0) {
            #pragma unroll
            for (int k = 0; k < 4; ++k) {
                const int t = tg + (k << 4);
                *reinterpret_cast<float2*>(&P_lds[t * 12 + h0]) =
                    make_float2(e0v[k] * inv0, e1v[k] * inv1);
            }
            if (tg == 0) {
                red_pc[h0]     = ec0 * inv0;
                red_pc[h0 + 1] = ec1 * inv1;
            }
        }
        __syncthreads();   // bar: P complete

        // ---- phase D: wave w sums its 16 tokens; lane = (h-half, f4 col) ----
        const int hl  = l >> 5;
        const int fc2 = l & 31;
        float4 pacc[4];
        #pragma unroll
        for (int j = 0; j < 4; ++j) pacc[j] = make_float4(0.f, 0.f, 0.f, 0.f);
        #pragma unroll
        for (int tt = 0; tt < 16; ++tt) {
            const int t = w * 16 + tt;
            const uint2 u = nb2[(t << 5) | (fc2 ^ (t & 7))];
            const float2 ta = unp_h2(u.x), tb = unp_h2(u.y);
            const float t0 = ta.x, t1 = ta.y, t2 = tb.x, t3 = tb.y;
            const float4 pv = ((const float4*)P_lds)[t * 3 + hl];
            pacc[0].x = fmaf(pv.x, t0, pacc[0].x); pacc[0].y = fmaf(pv.x, t1, pacc[0].y);
            pacc[0].z = fmaf(pv.x, t2, pacc[0].z); pacc[0].w = fmaf(pv.x, t3, pacc[0].w);
            pacc[1].x = fmaf(pv.y, t0, pacc[1].x); pacc[1].y = fmaf(pv.y, t1, pacc[1].y);
            pacc[1].z = fmaf(pv.y, t2, pacc[1].z); pacc[1].w = fmaf(pv.y, t3, pacc[1].w);
            pacc[2].x = fmaf(pv.z, t0, pacc[2].x); pacc[2].y = fmaf(pv.z, t1, pacc[2].y);
            pacc[2].z = fmaf(pv.z, t2, pacc[2].z); pacc[2].w = fmaf(pv.z, t3, pacc[2].w);
            pacc[3].x = fmaf(pv.w, t0, pacc[3].x); pacc[3].y = fmaf(pv.w, t1, pacc[3].y);
            pacc[3].z = fmaf(pv.w, t2, pacc[3].z); pacc[3].w = fmaf(pv.w, t3, pacc[3].w);
        }
        // partials (f32) overlay the wave's OWN dead f16 token rows (4 KB each)
        #pragma unroll
        for (int j = 0; j < 4; ++j)
            ((float4*)nb_lds)[w * 256 + (hl * 4 + j) * 32 + fc2] = pacc[j];
        __syncthreads();   // bar: partials ready

        // ---- phase E: combine partials + center seed; write s (bf16, linear) ----
        {
            const int hE = tid >> 5;
            const int fE = tid & 31;
            float4 sum = make_float4(0.f, 0.f, 0.f, 0.f);
            #pragma unroll
            for (int ww = 0; ww < 4; ++ww) {
                const float4 p = ((const float4*)nb_lds)[ww * 256 + hE * 32 + fE];
                sum.x += p.x; sum.y += p.y; sum.z += p.z; sum.w += p.w;
            }
            const float pc = red_pc[hE];
            const float4 cc = c4r[rot32(fE)];
            sum.x = fmaf(pc, cc.x, sum.x);
            sum.y = fmaf(pc, cc.y, sum.y);
            sum.z = fmaf(pc, cc.z, sum.z);
            sum.w = fmaf(pc, cc.w, sum.w);
            qs8u[bb * 256 + tid] =
                make_uint2(pack_bf2(sum.x, sum.y), pack_bf2(sum.z, sum.w));
        }
        __syncthreads();   // bar: partials consumed; next commit may overwrite nb
    }

    // ================= k3-part: out = s8 @ M_bf16 (simple loop, r16-proven) =================
    {
        const int cg = tid & 31;
        const int kg = tid >> 5;
        const int c4i = cg << 2;
        const int kbase = kg << 7;

        float4 acc[NB];
        #pragma unroll
        for (int r = 0; r < NB; ++r) acc[r] = make_float4(0.f, 0.f, 0.f, 0.f);

        const uint2* Mp2 = (const uint2*)Mb;
        const unsigned short* sp = (const unsigned short*)qs8f;

        #pragma unroll 4
        for (int ki = 0; ki < 128; ++ki) {
            const int k = kbase + ki;
            const uint2 u = Mp2[(size_t)k * 32 + cg];
            const float4 mv = unp4(u);
            #pragma unroll
            for (int r = 0; r < NB; ++r) {
                const float sv = bfs(sp[r * 1024 + k]);   // broadcast within group
                acc[r].x = fmaf(sv, mv.x, acc[r].x);
                acc[r].y = fmaf(sv, mv.y, acc[r].y);
                acc[r].z = fmaf(sv, mv.z, acc[r].z);
                acc[r].w = fmaf(sv, mv.w, acc[r].w);
            }
        }
        __syncthreads();                   // all s reads done; nb+qs8 regions free
        // partials: 32 KB split across nb_lds (kg 0-3) and qs8f (kg 4-7)
        float* baseW = (kg < 4) ? nb_lds : qs8f;
        const int kgm = kg & 3;
        #pragma unroll
        for (int r = 0; r < NB; ++r)
            *reinterpret_cast<float4*>(&baseW[(kgm * 8 + r) * 128 + c4i]) = acc[r];
        __syncthreads();

        {
            const int r = tid >> 5;
            float4 sum = make_float4(0.f, 0.f, 0.f, 0.f);
            #pragma unroll
            for (int g = 0; g < 8; ++g) {
                const float* bg = (g < 4) ? nb_lds : qs8f;
                const float4 p = *reinterpret_cast<const float4*>(
                    &bg[((g & 3) * 8 + r) * 128 + c4i]);
                sum.x += p.x; sum.y += p.y; sum.z += p.z; sum.w += p.w;
            }
            *reinterpret_cast<float4*>(out + (rb + r) * D + c4i) = sum;
        }
    }
}

} // namespace

extern "C" void kernel_launch(void* const* d_in, const int* in_sizes, int n_in,
                              void* d_out, int out_size, void* d_ws, size_t ws_size,
                              hipStream_t stream) {
    const float* center    = (const float*)d_in[0];
    const float* neighbors = (const float*)d_in[1];
    const float* WQ        = (const float*)d_in[2];
    const float* WK        = (const float*)d_in[3];
    const float* WV        = (const float*)d_in[4];
    const float* WO        = (const float*)d_in[5];
    float* outp            = (float*)d_out;

    const int B = in_sizes[0] / D;   // 8192

    unsigned short* Nb = (unsigned short*)d_ws;          // 128*1024 bf16 (256 KB)
    unsigned short* Mb = Nb + 128 * 1024;                // 1024*128 bf16 (256 KB)

    hipLaunchKernelGGL(k0_nm,   dim3(512),    dim3(256), 0, stream, WQ, WK, WV, WO, Nb, Mb);
    hipLaunchKernelGGL(k_fused, dim3(B / NB), dim3(256), 0, stream, center, neighbors, Nb, Mb, outp);
}

// Round 20
// 110.534 us; speedup vs baseline: 2.5072x; 1.1920x over previous
//
#include <hip/hip_runtime.h>
#include <hip/hip_bf16.h>
#include <math.h>

namespace {

constexpr int D  = 128;
constexpr int TN = 64;
constexpr int NB = 8;     // batches per fused block

typedef _Float16 h2 __attribute__((ext_vector_type(2)));

__device__ __forceinline__ unsigned pack_h2(float a, float b) {
    h2 v; v.x = (_Float16)a; v.y = (_Float16)b;
    return __builtin_bit_cast(unsigned, v);
}
__device__ __forceinline__ float2 unp_h2(unsigned u) {
    h2 v = __builtin_bit_cast(h2, u);
    return make_float2((float)v.x, (float)v.y);
}
__device__ __forceinline__ float fdot2f(unsigned a, unsigned b, float c) {
#if __has_builtin(__builtin_amdgcn_fdot2)
    return __builtin_amdgcn_fdot2(__builtin_bit_cast(h2, a),
                                  __builtin_bit_cast(h2, b), c, false);
#else
    const float2 fa = unp_h2(a), fb = unp_h2(b);
    return fmaf(fa.x, fb.x, fmaf(fa.y, fb.y, c));
#endif
}

// d_ws layout (both k-paired f16):
//   N2 [64][1024]  uint (pairs over k of N[128][1024])   256 KB
//   M2 [512][128]  uint (pairs over k of M[1024][128])   256 KB

// ---------------- K0: precompute N2 and M2 (k-paired f16) ----------------
__global__ __launch_bounds__(256)
void k0_nm(const float* __restrict__ WQ, const float* __restrict__ WK,
           const float* __restrict__ WV, const float* __restrict__ WO,
           unsigned* __restrict__ N2, unsigned* __restrict__ M2)
{
    const int t = blockIdx.x * 256 + threadIdx.x;   // 0..65535
    {   // N2[kk][col]: pair of N[2kk][col], N[2kk+1][col]
        const int kk = t >> 10, col = t & 1023;
        const int h = col >> 7, d = col & 127;
        const float* wq0 = WQ + (size_t)(2 * kk) * D + h * 16;
        const float* wq1 = wq0 + D;
        const float* wk  = WK + (size_t)d * D + h * 16;
        float a0 = 0.f, a1 = 0.f;
        #pragma unroll
        for (int j = 0; j < 16; ++j) {
            a0 = fmaf(wq0[j], wk[j], a0);
            a1 = fmaf(wq1[j], wk[j], a1);
        }
        N2[t] = pack_h2(0.25f * a0, 0.25f * a1);
    }
    {   // M2[kk][e]: pair of M[2kk][e], M[2kk+1][e];  k = h*128+d
        const int kk = t >> 7, e = t & 127;
        const int k0 = 2 * kk;
        const int h = k0 >> 7, d = k0 & 127;          // d even -> d,d+1 same h-block
        const float* wv0 = WV + (size_t)d * D + h * 16;
        const float* wv1 = wv0 + D;
        const float* wo  = WO + (size_t)(h * 16) * D + e;
        float b0 = 0.f, b1 = 0.f;
        #pragma unroll
        for (int j = 0; j < 16; ++j) {
            const float w_ = wo[(size_t)j * D];
            b0 = fmaf(wv0[j], w_, b0);
            b1 = fmaf(wv1[j], w_, b1);
        }
        M2[t] = pack_h2(b0, b1);
    }
}

// ---------------- fused: qk=c@N2 -> 8x attention -> out=s@M2 (all-fdot2) ----------------
// r18 spill-free config; r19 attention body; k1/k3 now 2-MAC fdot2 loops.
// LDS ~37.9 KB -> 4 blocks/CU.
__global__ __launch_bounds__(256, 2)
void k_fused(const float* __restrict__ center, const float* __restrict__ neighbors,
             const unsigned* __restrict__ N2, const unsigned* __restrict__ M2,
             float* __restrict__ out)
{
    __shared__ __align__(16) float nb_lds[TN * D / 2];  // 16 KB f16 tokens; uint2 slot (t<<5)|(fc^(t&7))
    __shared__ __align__(16) float qs8f[NB * 512];      // 16 KB f16: qk (rotated) -> s (k-paired linear)
    __shared__ __align__(16) unsigned c2u[NB * 64];     // 2 KB f16 k-paired center rows
    __shared__ float P_lds[TN * 12];                    // 3 KB
    __shared__ float red_pc[8];

    const int tid = threadIdx.x;           // 0..255
    const int w   = tid >> 6;              // wave 0..3 (attention: owns heads 2w,2w+1)
    const int l   = tid & 63;
    const size_t rb = (size_t)blockIdx.x * NB;

    uint2* nbu  = (uint2*)nb_lds;
    uint2* qs8u = (uint2*)qs8f;

    // ---- stage c2 (k-paired f16) ----
    {
        const int r = tid >> 5, f = tid & 31;
        const float4 g = ((const float4*)(center + (rb + r) * (size_t)D))[f];
        c2u[r * 64 + 2 * f]     = pack_h2(g.x, g.y);
        c2u[r * 64 + 2 * f + 1] = pack_h2(g.z, g.w);
    }
    __syncthreads();                       // c2 visible

    // ================= k1-part: qk8 = c @ N (fdot2, k-paired) =================
    {
        const uint4* N2u4 = (const uint4*)N2;   // row kk = 256 uint4
        float4 acc[NB];
        #pragma unroll
        for (int r = 0; r < NB; ++r) acc[r] = make_float4(0.f, 0.f, 0.f, 0.f);

        #pragma unroll 4
        for (int kk = 0; kk < 64; ++kk) {
            const uint4 u = N2u4[(size_t)kk * 256 + tid];   // 4 cols' k-pair
            #pragma unroll
            for (int r = 0; r < NB; ++r) {
                const unsigned cp = c2u[r * 64 + kk];       // broadcast
                acc[r].x = fdot2f(cp, u.x, acc[r].x);
                acc[r].y = fdot2f(cp, u.y, acc[r].y);
                acc[r].z = fdot2f(cp, u.z, acc[r].z);
                acc[r].w = fdot2f(cp, u.w, acc[r].w);
            }
        }
        const int fc = tid & 31;
        const int qslot = (tid & ~31) | (((fc & 7) << 2) | (fc >> 3));  // rotated qk layout
        #pragma unroll
        for (int r = 0; r < NB; ++r)
            qs8u[r * 256 + qslot] =
                make_uint2(pack_h2(acc[r].x, acc[r].y), pack_h2(acc[r].z, acc[r].w));
    }

    // ---- NOW load batch-0 nb into staging regs (not live across the GEMM above) ----
    float4 st[8];
    {
        const float4* g0 = (const float4*)(neighbors + rb * TN * D);
        #pragma unroll
        for (int i = 0; i < 8; ++i) st[i] = g0[i * 256 + tid];
    }
    __syncthreads();                       // qk visible

    // ================= per-batch attention loop (r19-proven body) =================
    #pragma unroll 1
    for (int bb = 0; bb < NB; ++bb) {
        // ---- commit staged nb registers -> f16 swizzled LDS ----
        #pragma unroll
        for (int i = 0; i < 8; ++i) {
            const int fi = i * 256 + tid;
            const int t  = fi >> 5;
            const int fc = fi & 31;
            nbu[(t << 5) | (fc ^ (t & 7))] =
                make_uint2(pack_h2(st[i].x, st[i].y), pack_h2(st[i].z, st[i].w));
        }
        __syncthreads();                   // nb staged

        // ---- issue next batch's nb loads; they fly during phases A-E ----
        if (bb + 1 < NB) {
            const float4* gn = (const float4*)(neighbors + (rb + bb + 1) * TN * D);
            #pragma unroll
            for (int i = 0; i < 8; ++i) st[i] = gn[i * 256 + tid];
        }

        const uint2*    nb2 = (const uint2*)nb_lds;
        const uint2*    qku = qs8u + bb * 256;
        const unsigned* cb2 = c2u + bb * 64;

        // ---- phase A: wave w scores all 64 tokens for heads 2w,2w+1; wave-local softmax ----
        const int tg = l & 15;
        const int q  = l >> 4;
        const int h0 = 2 * w;

        float sc0[4] = {0.f, 0.f, 0.f, 0.f};
        float sc1[4] = {0.f, 0.f, 0.f, 0.f};
        float s0a = 0.f, s0b = 0.f;
        #pragma unroll
        for (int jj = 0; jj < 8; ++jj) {
            const int rfc = (jj << 2) | q;     // rotated slot of fc=(q<<3)|jj
            const int fc  = (q << 3) | jj;
            const uint2 kv0p = qku[h0 * 32 + rfc];
            const uint2 kv1p = qku[(h0 + 1) * 32 + rfc];
            const unsigned cpa = cb2[2 * fc], cpb = cb2[2 * fc + 1];
            s0a = fdot2f(cpa, kv0p.x, fdot2f(cpb, kv0p.y, s0a));
            s0b = fdot2f(cpa, kv1p.x, fdot2f(cpb, kv1p.y, s0b));
            #pragma unroll
            for (int k = 0; k < 4; ++k) {
                const int t = tg + (k << 4);
                const uint2 u = nb2[(t << 5) | (fc ^ (t & 7))];
                sc0[k] = fdot2f(u.x, kv0p.x, fdot2f(u.y, kv0p.y, sc0[k]));
                sc1[k] = fdot2f(u.x, kv1p.x, fdot2f(u.y, kv1p.y, sc1[k]));
            }
        }
        #pragma unroll
        for (int k = 0; k < 4; ++k) {
            sc0[k] += __shfl_xor(sc0[k], 16);  sc0[k] += __shfl_xor(sc0[k], 32);
            sc1[k] += __shfl_xor(sc1[k], 16);  sc1[k] += __shfl_xor(sc1[k], 32);
        }
        s0a += __shfl_xor(s0a, 16);  s0a += __shfl_xor(s0a, 32);
        s0b += __shfl_xor(s0b, 16);  s0b += __shfl_xor(s0b, 32);

        float m0 = fmaxf(fmaxf(sc0[0], sc0[1]), fmaxf(sc0[2], sc0[3]));
        float m1 = fmaxf(fmaxf(sc1[0], sc1[1]), fmaxf(sc1[2], sc1[3]));
        #pragma unroll
        for (int off = 8; off >= 1; off >>= 1) {
            m0 = fmaxf(m0, __shfl_xor(m0, off));
            m1 = fmaxf(m1, __shfl_xor(m1, off));
        }
        m0 = fmaxf(m0, s0a);
        m1 = fmaxf(m1, s0b);
        float e0v[4], e1v[4];
        float sum0 = 0.f, sum1 = 0.f;
        #pragma unroll
        for (int k = 0; k < 4; ++k) {
            e0v[k] = __expf(sc0[k] - m0);  sum0 += e0v[k];
            e1v[k] = __expf(sc1[k] - m1);  sum1 += e1v[k];
        }
        #pragma unroll
        for (int off = 8; off >= 1; off >>= 1) {
            sum0 += __shfl_xor(sum0, off);
            sum1 += __shfl_xor(sum1, off);
        }
        const float ec0 = __expf(s0a - m0);
        const float ec1 = __expf(s0b - m1);
        const float inv0 = 1.0f / (sum0 + ec0);
        const float inv1 = 1.0f / (sum1 + ec1);
        if (q == 0) {
            #pragma unroll
            for (int k = 0; k < 4; ++k) {
                const int t = tg + (k << 4);
                *reinterpret_cast<float2*>(&P_lds[t * 12 + h0]) =
                    make_float2(e0v[k] * inv0, e1v[k] * inv1);
            }
            if (tg == 0) {
                red_pc[h0]     = ec0 * inv0;
                red_pc[h0 + 1] = ec1 * inv1;
            }
        }
        __syncthreads();   // bar: P complete

        // ---- phase D: wave w sums its 16 tokens; lane = (h-half, f4 col) ----
        const int hl  = l >> 5;
        const int fc2 = l & 31;
        float4 pacc[4];
        #pragma unroll
        for (int j = 0; j < 4; ++j) pacc[j] = make_float4(0.f, 0.f, 0.f, 0.f);
        #pragma unroll
        for (int tt = 0; tt < 16; ++tt) {
            const int t = w * 16 + tt;
            const uint2 u = nb2[(t << 5) | (fc2 ^ (t & 7))];
            const float2 ta = unp_h2(u.x), tb = unp_h2(u.y);
            const float t0 = ta.x, t1 = ta.y, t2 = tb.x, t3 = tb.y;
            const float4 pv = ((const float4*)P_lds)[t * 3 + hl];
            pacc[0].x = fmaf(pv.x, t0, pacc[0].x); pacc[0].y = fmaf(pv.x, t1, pacc[0].y);
            pacc[0].z = fmaf(pv.x, t2, pacc[0].z); pacc[0].w = fmaf(pv.x, t3, pacc[0].w);
            pacc[1].x = fmaf(pv.y, t0, pacc[1].x); pacc[1].y = fmaf(pv.y, t1, pacc[1].y);
            pacc[1].z = fmaf(pv.y, t2, pacc[1].z); pacc[1].w = fmaf(pv.y, t3, pacc[1].w);
            pacc[2].x = fmaf(pv.z, t0, pacc[2].x); pacc[2].y = fmaf(pv.z, t1, pacc[2].y);
            pacc[2].z = fmaf(pv.z, t2, pacc[2].z); pacc[2].w = fmaf(pv.z, t3, pacc[2].w);
            pacc[3].x = fmaf(pv.w, t0, pacc[3].x); pacc[3].y = fmaf(pv.w, t1, pacc[3].y);
            pacc[3].z = fmaf(pv.w, t2, pacc[3].z); pacc[3].w = fmaf(pv.w, t3, pacc[3].w);
        }
        // partials (f32) overlay the wave's OWN dead f16 token rows (4 KB each)
        #pragma unroll
        for (int j = 0; j < 4; ++j)
            ((float4*)nb_lds)[w * 256 + (hl * 4 + j) * 32 + fc2] = pacc[j];
        __syncthreads();   // bar: partials ready

        // ---- phase E: combine partials + center seed; write s (f16 k-paired, linear) ----
        {
            const int hE = tid >> 5;
            const int fE = tid & 31;
            float4 sum = make_float4(0.f, 0.f, 0.f, 0.f);
            #pragma unroll
            for (int ww = 0; ww < 4; ++ww) {
                const float4 p = ((const float4*)nb_lds)[ww * 256 + hE * 32 + fE];
                sum.x += p.x; sum.y += p.y; sum.z += p.z; sum.w += p.w;
            }
            const float pc = red_pc[hE];
            const float2 ca = unp_h2(cb2[2 * fE]), cb = unp_h2(cb2[2 * fE + 1]);
            sum.x = fmaf(pc, ca.x, sum.x);
            sum.y = fmaf(pc, ca.y, sum.y);
            sum.z = fmaf(pc, cb.x, sum.z);
            sum.w = fmaf(pc, cb.y, sum.w);
            qs8u[bb * 256 + tid] =
                make_uint2(pack_h2(sum.x, sum.y), pack_h2(sum.z, sum.w));
        }
        __syncthreads();   // bar: partials consumed; next commit may overwrite nb
    }

    // ================= k3-part: out = s @ M (fdot2, k-paired) =================
    {
        const int cg = tid & 31;
        const int kg = tid >> 5;
        const int c4i = cg << 2;
        const int kb2 = kg << 6;           // kk base (64 pairs per k-split group)

        float4 acc[NB];
        #pragma unroll
        for (int r = 0; r < NB; ++r) acc[r] = make_float4(0.f, 0.f, 0.f, 0.f);

        const uint4* M2u4 = (const uint4*)M2;           // row kk = 32 uint4
        const unsigned* sp2 = (const unsigned*)qs8f;    // s pairs: [r*512 + kk]

        #pragma unroll 4
        for (int k2 = 0; k2 < 64; ++k2) {
            const int kk = kb2 + k2;
            const uint4 u = M2u4[(size_t)kk * 32 + cg];
            #pragma unroll
            for (int r = 0; r < NB; ++r) {
                const unsigned sv = sp2[r * 512 + kk];  // broadcast
                acc[r].x = fdot2f(sv, u.x, acc[r].x);
                acc[r].y = fdot2f(sv, u.y, acc[r].y);
                acc[r].z = fdot2f(sv, u.z, acc[r].z);
                acc[r].w = fdot2f(sv, u.w, acc[r].w);
            }
        }
        __syncthreads();                   // all s reads done; nb+qs8 regions free
        // partials: 32 KB split across nb_lds (kg 0-3) and qs8f (kg 4-7)
        float* baseW = (kg < 4) ? nb_lds : qs8f;
        const int kgm = kg & 3;
        #pragma unroll
        for (int r = 0; r < NB; ++r)
            *reinterpret_cast<float4*>(&baseW[(kgm * 8 + r) * 128 + c4i]) = acc[r];
        __syncthreads();

        {
            const int r = tid >> 5;
            float4 sum = make_float4(0.f, 0.f, 0.f, 0.f);
            #pragma unroll
            for (int g = 0; g < 8; ++g) {
                const float* bg = (g < 4) ? nb_lds : qs8f;
                const float4 p = *reinterpret_cast<const float4*>(
                    &bg[((g & 3) * 8 + r) * 128 + c4i]);
                sum.x += p.x; sum.y += p.y; sum.z += p.z; sum.w += p.w;
            }
            *reinterpret_cast<float4*>(out + (rb + r) * D + c4i) = sum;
        }
    }
}

} // namespace

extern "C" void kernel_launch(void* const* d_in, const int* in_sizes, int n_in,
                              void* d_out, int out_size, void* d_ws, size_t ws_size,
                              hipStream_t stream) {
    const float* center    = (const float*)d_in[0];
    const float* neighbors = (const float*)d_in[1];
    const float* WQ        = (const float*)d_in[2];
    const float* WK        = (const float*)d_in[3];
    const float* WV        = (const float*)d_in[4];
    const float* WO        = (const float*)d_in[5];
    float* outp            = (float*)d_out;

    const int B = in_sizes[0] / D;   // 8192

    unsigned* N2 = (unsigned*)d_ws;          // 64*1024 uint (256 KB)
    unsigned* M2 = N2 + 64 * 1024;           // 512*128 uint (256 KB)

    hipLaunchKernelGGL(k0_nm,   dim3(256),    dim3(256), 0, stream, WQ, WK, WV, WO, N2, M2);
    hipLaunchKernelGGL(k_fused, dim3(B / NB), dim3(256), 0, stream, center, neighbors, N2, M2, outp);
}